// Round 1
// baseline (7670.052 us; speedup 1.0000x reference)
//
#include <hip/hip_runtime.h>

// Problem constants
#define B_TOT   4096          // 4*1024 batch rows
#define D_IN    2048
#define D_OUT   2048
#define NCHUNK  4
#define LIN     512
#define LOUT    512
#define RK      8             // ring rank R
#define KXS     4096          // LIN * RK, flattened (x,s) index
#define CORE_R_STRIDE 2097152 // LOUT*LIN*RK
#define CORE_O_STRIDE 4096    // LIN*RK

// Workspace layout (floats)
#define WS_XT    0                          // xT [2048][4096]           : 8388608
#define WS_GHAT  8388608                    // Ghat [4][8][512][8]       : 131072
#define WS_S     (8388608 + 131072)         // S    [4][4096][64]        : 1048576
#define WS_ENVT  (8388608 + 131072 + 1048576) // envT [4][64][4096]      : 1048576

// ---------------- Kernel 1: transpose x [4096][2048] -> xT [2048][4096] --------
__global__ __launch_bounds__(256) void k_transpose(const float* __restrict__ x,
                                                   float* __restrict__ xT) {
    __shared__ float tile[32][33];
    int b0 = blockIdx.x * 32;
    int c0 = blockIdx.y * 32;
    int tx = threadIdx.x;      // 0..31
    int ty = threadIdx.y;      // 0..7
#pragma unroll
    for (int j = 0; j < 4; ++j)
        tile[ty + j * 8][tx] = x[(size_t)(b0 + ty + j * 8) * D_IN + c0 + tx];
    __syncthreads();
#pragma unroll
    for (int j = 0; j < 4; ++j)
        xT[(size_t)(c0 + ty + j * 8) * B_TOT + b0 + tx] = tile[tx][ty + j * 8];
}

// ---------------- Kernel 2: Ghat[i][r][xs] = sum_o G_i[r][o][xs] ---------------
__global__ __launch_bounds__(256) void k_reduce_g(const float* __restrict__ g0,
                                                  const float* __restrict__ g1,
                                                  const float* __restrict__ g2,
                                                  const float* __restrict__ g3,
                                                  float* __restrict__ ghat) {
    int i = blockIdx.z;
    int r = blockIdx.y;
    int xs = blockIdx.x * 256 + threadIdx.x;   // 0..4095
    const float* G = (i == 0) ? g0 : (i == 1) ? g1 : (i == 2) ? g2 : g3;
    const float* base = G + (size_t)r * CORE_R_STRIDE + xs;
    float acc = 0.f;
#pragma unroll 8
    for (int o = 0; o < LOUT; ++o) acc += base[(size_t)o * CORE_O_STRIDE];
    ghat[(size_t)i * 32768 + r * 4096 + xs] = acc;
}

// ---------------- Kernel 3: S[i][b][r*8+s] = sum_x Ghat[i][r][x][s]*x[b][i*512+x]
__global__ __launch_bounds__(256) void k_s(const float* __restrict__ x,
                                           const float* __restrict__ ghat,
                                           float* __restrict__ S) {
    int i = blockIdx.y;
    int tid = threadIdx.x;
    int rs = tid & 63;
    int b = blockIdx.x * 4 + (tid >> 6);
    int r = rs >> 3, s = rs & 7;
    const float* gh = ghat + (size_t)i * 32768 + r * 4096 + s;
    const float* xr = x + (size_t)b * D_IN + i * LIN;
    float acc = 0.f;
#pragma unroll 8
    for (int xi = 0; xi < LIN; ++xi) acc = fmaf(gh[xi * 8], xr[xi], acc);
    S[(size_t)i * (B_TOT * 64) + b * 64 + rs] = acc;
}

// ---------------- Kernel 4: chain products -> envT ----------------------------
__device__ __forceinline__ float mm8(float A, float B, int lane) {
    // lane holds M[lane>>3][lane&7]; returns (A@B)[r][s]
    float c = 0.f;
#pragma unroll
    for (int p = 0; p < 8; ++p) {
        float a = __shfl(A, (lane & 56) | p, 64);
        float b = __shfl(B, (p << 3) | (lane & 7), 64);
        c = fmaf(a, b, c);
    }
    return c;
}
__device__ __forceinline__ float tr8(float E, int lane) {
    return __shfl(E, ((lane & 7) << 3) | (lane >> 3), 64);
}

__global__ __launch_bounds__(256) void k_env(const float* __restrict__ S,
                                             float* __restrict__ envT) {
    int tid = threadIdx.x;
    int lane = tid & 63;
    int b = blockIdx.x * 4 + (tid >> 6);
    float S0 = S[0 * (B_TOT * 64) + b * 64 + lane];
    float S1 = S[1 * (B_TOT * 64) + b * 64 + lane];
    float S2 = S[2 * (B_TOT * 64) + b * 64 + lane];
    float S3 = S[3 * (B_TOT * 64) + b * 64 + lane];

    float P1 = S0;
    float P2 = mm8(P1, S1, lane);
    float P3 = mm8(P2, S2, lane);
    float Q2 = S3;
    float Q1 = mm8(S2, Q2, lane);
    float Q0 = mm8(S1, Q1, lane);

    float e0 = tr8(Q0, lane);                 // (Q0 @ I)^T
    float e1 = tr8(mm8(Q1, P1, lane), lane);
    float e2 = tr8(mm8(Q2, P2, lane), lane);
    float e3 = tr8(P3, lane);                 // (I @ P3)^T

    envT[(size_t)(0 * 64 + lane) * B_TOT + b] = e0;
    envT[(size_t)(1 * 64 + lane) * B_TOT + b] = e1;
    envT[(size_t)(2 * 64 + lane) * B_TOT + b] = e2;
    envT[(size_t)(3 * 64 + lane) * B_TOT + b] = e3;
}

// ---------------- Kernel 5: main GEMM out_i = sum_r Z_{i,r} @ G_{i,r}^T --------
// BM=128 (b), BN=128 (o), BK=8 (xs). A generated on the fly: Z[b,k]=env[b,r,s]*x[b,x]
__global__ __launch_bounds__(256, 2) void k_gemm(const float* __restrict__ g0,
                                                 const float* __restrict__ g1,
                                                 const float* __restrict__ g2,
                                                 const float* __restrict__ g3,
                                                 const float* __restrict__ xT,
                                                 const float* __restrict__ envT,
                                                 const float* __restrict__ bias,
                                                 float* __restrict__ out) {
    const int i = blockIdx.z;
    const int b0 = blockIdx.x * 128;
    const int o0 = blockIdx.y * 128;
    const float* G = (i == 0) ? g0 : (i == 1) ? g1 : (i == 2) ? g2 : g3;
    const float* xTi = xT + (size_t)i * LIN * B_TOT;
    const float* eTi = envT + (size_t)i * 64 * B_TOT;

    __shared__ float Es[8][128];
    __shared__ float Xc[128];
    __shared__ float Bs[8][128];

    const int tid = threadIdx.x;
    const int tx = tid & 15;   // -> o
    const int ty = tid >> 4;   // -> b

    float acc[8][8];
#pragma unroll
    for (int a = 0; a < 8; ++a)
#pragma unroll
        for (int c = 0; c < 8; ++c) acc[a][c] = 0.f;

    for (int r = 0; r < 8; ++r) {
        // stage env slice for this r: Es[s][m] = envT[i][r*8+s][b0+m]
        {
            int k = tid >> 5, m = (tid & 31) * 4;
            *(float4*)&Es[k][m] = *(const float4*)&eTi[(size_t)(r * 8 + k) * B_TOT + b0 + m];
        }
        __syncthreads();
        float e[8][8];
#pragma unroll
        for (int kk = 0; kk < 8; ++kk) {
            *(float4*)&e[kk][0] = *(const float4*)&Es[kk][ty * 8];
            *(float4*)&e[kk][4] = *(const float4*)&Es[kk][ty * 8 + 4];
        }
        const float* Gr = G + (size_t)r * CORE_R_STRIDE;

        for (int k0 = 0; k0 < KXS; k0 += 8) {
            // stage x column (one x value per 8 k's): Xc[m] = xT[i*512 + k0/8][b0+m]
            if (tid < 32) {
                *(float4*)&Xc[tid * 4] =
                    *(const float4*)&xTi[(size_t)(k0 >> 3) * B_TOT + b0 + tid * 4];
            }
            // stage B tile: Bs[k][n] = G[r][o0+n][k0+k]
            {
                int n = tid >> 1, kq = (tid & 1) * 4;
                float4 gv = *(const float4*)&Gr[(size_t)(o0 + n) * CORE_O_STRIDE + k0 + kq];
                Bs[kq + 0][n] = gv.x;
                Bs[kq + 1][n] = gv.y;
                Bs[kq + 2][n] = gv.z;
                Bs[kq + 3][n] = gv.w;
            }
            __syncthreads();

            float xv[8];
            *(float4*)&xv[0] = *(const float4*)&Xc[ty * 8];
            *(float4*)&xv[4] = *(const float4*)&Xc[ty * 8 + 4];

#pragma unroll
            for (int kk = 0; kk < 8; ++kk) {
                float bf[8];
                *(float4*)&bf[0] = *(const float4*)&Bs[kk][tx * 8];
                *(float4*)&bf[4] = *(const float4*)&Bs[kk][tx * 8 + 4];
#pragma unroll
                for (int jm = 0; jm < 8; ++jm) {
                    float a = e[kk][jm] * xv[jm];
#pragma unroll
                    for (int jn = 0; jn < 8; ++jn)
                        acc[jm][jn] = fmaf(a, bf[jn], acc[jm][jn]);
                }
            }
            __syncthreads();
        }
    }

    // epilogue: out[b][i*512 + o] = acc + bias
    float bv[8];
#pragma unroll
    for (int jn = 0; jn < 8; ++jn) bv[jn] = bias[i * LOUT + o0 + tx * 8 + jn];
#pragma unroll
    for (int jm = 0; jm < 8; ++jm) {
        size_t row = (size_t)(b0 + ty * 8 + jm) * D_OUT + i * LOUT + o0 + tx * 8;
        float4 v0 = make_float4(acc[jm][0] + bv[0], acc[jm][1] + bv[1],
                                acc[jm][2] + bv[2], acc[jm][3] + bv[3]);
        float4 v1 = make_float4(acc[jm][4] + bv[4], acc[jm][5] + bv[5],
                                acc[jm][6] + bv[6], acc[jm][7] + bv[7]);
        *(float4*)&out[row] = v0;
        *(float4*)&out[row + 4] = v1;
    }
}

extern "C" void kernel_launch(void* const* d_in, const int* in_sizes, int n_in,
                              void* d_out, int out_size, void* d_ws, size_t ws_size,
                              hipStream_t stream) {
    const float* x    = (const float*)d_in[0];
    const float* g0   = (const float*)d_in[1];
    const float* g1   = (const float*)d_in[2];
    const float* g2   = (const float*)d_in[3];
    const float* g3   = (const float*)d_in[4];
    const float* bias = (const float*)d_in[5];
    float* out = (float*)d_out;
    float* ws = (float*)d_ws;

    float* xT   = ws + WS_XT;
    float* ghat = ws + WS_GHAT;
    float* S    = ws + WS_S;
    float* envT = ws + WS_ENVT;

    // 1. transpose x
    k_transpose<<<dim3(128, 64), dim3(32, 8), 0, stream>>>(x, xT);
    // 2. Ghat
    k_reduce_g<<<dim3(16, 8, 4), 256, 0, stream>>>(g0, g1, g2, g3, ghat);
    // 3. S
    k_s<<<dim3(1024, 4), 256, 0, stream>>>(x, ghat, S);
    // 4. env chain
    k_env<<<1024, 256, 0, stream>>>(S, envT);
    // 5. main GEMM (grid: 32 b-tiles x 4 o-tiles x 4 chunks)
    k_gemm<<<dim3(32, 4, 4), 256, 0, stream>>>(g0, g1, g2, g3, xT, envT, bias, out);
}

// Round 3
// 2325.888 us; speedup vs baseline: 3.2977x; 3.2977x over previous
//
#include <hip/hip_runtime.h>

// Problem constants
#define B_TOT   4096          // 4*1024 batch rows
#define D_IN    2048
#define D_OUT   2048
#define NCHUNK  4
#define LIN     512
#define LOUT    512
#define RK      8             // ring rank R
#define KXS     4096          // LIN * RK, flattened (x,s) index, s innermost
#define CORE_R_STRIDE 2097152 // LOUT*LIN*RK
#define CORE_O_STRIDE 4096    // LIN*RK

// Workspace layout (floats)
#define WS_XT    0                          // xT [2048][4096]           : 8388608
#define WS_GHAT  8388608                    // Ghat [4][8][512][8]       : 131072
#define WS_S     (8388608 + 131072)         // S    [4][4096][64]        : 1048576
#define WS_ENVT  (8388608 + 131072 + 1048576) // envT [4][64][4096]      : 1048576

typedef __attribute__((ext_vector_type(8))) __bf16 bf16x8;
typedef __attribute__((ext_vector_type(4))) float f32x4;
typedef __attribute__((ext_vector_type(4))) unsigned int u32x4;

// ---------------- Kernel 1: transpose x [4096][2048] -> xT [2048][4096] --------
__global__ __launch_bounds__(256) void k_transpose(const float* __restrict__ x,
                                                   float* __restrict__ xT) {
    __shared__ float tile[32][33];
    int b0 = blockIdx.x * 32;
    int c0 = blockIdx.y * 32;
    int tx = threadIdx.x;      // 0..31
    int ty = threadIdx.y;      // 0..7
#pragma unroll
    for (int j = 0; j < 4; ++j)
        tile[ty + j * 8][tx] = x[(size_t)(b0 + ty + j * 8) * D_IN + c0 + tx];
    __syncthreads();
#pragma unroll
    for (int j = 0; j < 4; ++j)
        xT[(size_t)(c0 + ty + j * 8) * B_TOT + b0 + tx] = tile[tx][ty + j * 8];
}

// ---------------- Kernel 2: Ghat[i][r][xs] = sum_o G_i[r][o][xs] ---------------
__global__ __launch_bounds__(256) void k_reduce_g(const float* __restrict__ g0,
                                                  const float* __restrict__ g1,
                                                  const float* __restrict__ g2,
                                                  const float* __restrict__ g3,
                                                  float* __restrict__ ghat) {
    int i = blockIdx.z;
    int r = blockIdx.y;
    int xs = blockIdx.x * 256 + threadIdx.x;   // 0..4095
    const float* G = (i == 0) ? g0 : (i == 1) ? g1 : (i == 2) ? g2 : g3;
    const float* base = G + (size_t)r * CORE_R_STRIDE + xs;
    float acc = 0.f;
#pragma unroll 8
    for (int o = 0; o < LOUT; ++o) acc += base[(size_t)o * CORE_O_STRIDE];
    ghat[(size_t)i * 32768 + r * 4096 + xs] = acc;
}

// ---------------- Kernel 3: S[i][b][r*8+s] = sum_x Ghat[i][r][x][s]*x[b][i*512+x]
__global__ __launch_bounds__(256) void k_s(const float* __restrict__ x,
                                           const float* __restrict__ ghat,
                                           float* __restrict__ S) {
    int i = blockIdx.y;
    int tid = threadIdx.x;
    int rs = tid & 63;
    int b = blockIdx.x * 4 + (tid >> 6);
    int r = rs >> 3, s = rs & 7;
    const float* gh = ghat + (size_t)i * 32768 + r * 4096 + s;
    const float* xr = x + (size_t)b * D_IN + i * LIN;
    float acc = 0.f;
#pragma unroll 8
    for (int xi = 0; xi < LIN; ++xi) acc = fmaf(gh[xi * 8], xr[xi], acc);
    S[(size_t)i * (B_TOT * 64) + b * 64 + rs] = acc;
}

// ---------------- Kernel 4: chain products -> envT ----------------------------
__device__ __forceinline__ float mm8(float A, float B, int lane) {
    float c = 0.f;
#pragma unroll
    for (int p = 0; p < 8; ++p) {
        float a = __shfl(A, (lane & 56) | p, 64);
        float b = __shfl(B, (p << 3) | (lane & 7), 64);
        c = fmaf(a, b, c);
    }
    return c;
}
__device__ __forceinline__ float tr8(float E, int lane) {
    return __shfl(E, ((lane & 7) << 3) | (lane >> 3), 64);
}

__global__ __launch_bounds__(256) void k_env(const float* __restrict__ S,
                                             float* __restrict__ envT) {
    int tid = threadIdx.x;
    int lane = tid & 63;
    int b = blockIdx.x * 4 + (tid >> 6);
    float S0 = S[0 * (B_TOT * 64) + b * 64 + lane];
    float S1 = S[1 * (B_TOT * 64) + b * 64 + lane];
    float S2 = S[2 * (B_TOT * 64) + b * 64 + lane];
    float S3 = S[3 * (B_TOT * 64) + b * 64 + lane];

    float P1 = S0;
    float P2 = mm8(P1, S1, lane);
    float P3 = mm8(P2, S2, lane);
    float Q2 = S3;
    float Q1 = mm8(S2, Q2, lane);
    float Q0 = mm8(S1, Q1, lane);

    float e0 = tr8(Q0, lane);
    float e1 = tr8(mm8(Q1, P1, lane), lane);
    float e2 = tr8(mm8(Q2, P2, lane), lane);
    float e3 = tr8(P3, lane);

    envT[(size_t)(0 * 64 + lane) * B_TOT + b] = e0;
    envT[(size_t)(1 * 64 + lane) * B_TOT + b] = e1;
    envT[(size_t)(2 * 64 + lane) * B_TOT + b] = e2;
    envT[(size_t)(3 * 64 + lane) * B_TOT + b] = e3;
}

// ---------------- split helper: two fp32 -> packed bf16 hi pair + lo pair ------
// hi = truncate-to-bf16(v); lo = truncate-to-bf16(v - hi)  (residual capture
// makes the truncation bias negligible: combined error ~2^-16 relative)
// returns {hi_packed, lo_packed} by value (ext-vector elements can't bind refs)
__device__ __forceinline__ uint2 split2(float a, float b) {
    unsigned int ua = __float_as_uint(a), ub = __float_as_uint(b);
    unsigned int h = (ub & 0xffff0000u) | (ua >> 16);
    float la = a - __uint_as_float(ua & 0xffff0000u);
    float lb = b - __uint_as_float(ub & 0xffff0000u);
    unsigned int l = (__float_as_uint(lb) & 0xffff0000u) | (__float_as_uint(la) >> 16);
    return make_uint2(h, l);
}

// ---------------- Kernel 5: MFMA GEMM out_i = sum_r Z_{i,r} @ G_{i,r}^T --------
// Split-bf16 3-product emulation. BM=128 (b), BN=128 (o), BK=32 (k=(x,s)).
// A (=env*x) generated on the fly directly in MFMA A-fragment layout:
//   A[m=lane&15][k=quad*8+j], k=(x,s): s=j, x=kk*4+quad.
// B (=G[o][k]) staged via LDS as bf16 hi/lo.
__global__ __launch_bounds__(256, 2) void k_gemm_mfma(const float* __restrict__ g0,
                                                      const float* __restrict__ g1,
                                                      const float* __restrict__ g2,
                                                      const float* __restrict__ g3,
                                                      const float* __restrict__ xT,
                                                      const float* __restrict__ envT,
                                                      const float* __restrict__ bias,
                                                      float* __restrict__ out) {
    // Block decode with XCD swizzle: blocks of one (o-tile,chunk) combo share an
    // XCD (round-robin heuristic: xcd = linear_block_id % 8) for L2 reuse of G.
    int l = blockIdx.x;                       // 0..511
    int c = (l & 7) | (((l >> 3) >> 5) << 3); // combo 0..15
    int b_idx = (l >> 3) & 31;                // b-tile 0..31
    int i = c >> 2;                           // chunk
    int o0 = (c & 3) * 128;
    int b0 = b_idx * 128;

    const float* G = (i == 0) ? g0 : (i == 1) ? g1 : (i == 2) ? g2 : g3;
    const float* xTi = xT + (size_t)i * LIN * B_TOT;
    const float* eTi = envT + (size_t)i * 64 * B_TOT;

    __shared__ __align__(16) short Bhi[128 * 32];
    __shared__ __align__(16) short Blo[128 * 32];
    __shared__ float Xs[4][160];   // stride 160 -> conflict-free quad reads

    const int tid = threadIdx.x;
    const int lane = tid & 63;
    const int wave = tid >> 6;
    const int wm = (wave >> 1) * 64;
    const int wn = (wave & 1) * 64;
    const int l15 = lane & 15;
    const int quad = lane >> 4;

    f32x4 acc[4][4];
#pragma unroll
    for (int mf = 0; mf < 4; ++mf)
#pragma unroll
        for (int nf = 0; nf < 4; ++nf) acc[mf][nf] = (f32x4){0.f, 0.f, 0.f, 0.f};

    // B staging assignment: thread -> (row o_local, 16-k half)
    const int so = tid >> 1;
    const int sh = (tid & 1) * 16;
    const float* gbase = G + (size_t)(o0 + so) * CORE_O_STRIDE + sh;

    for (int r = 0; r < 8; ++r) {
        // env for this r: e[mf][s], held in registers for 128 K-steps
        float e[4][8];
#pragma unroll
        for (int mf = 0; mf < 4; ++mf) {
            int m = b0 + wm + mf * 16 + l15;
#pragma unroll
            for (int s = 0; s < 8; ++s)
                e[mf][s] = eTi[(size_t)(r * 8 + s) * B_TOT + m];
        }
        const float* Gr = gbase + (size_t)r * CORE_R_STRIDE;

        for (int kk = 0; kk < 128; ++kk) {
            const int k0 = kk * 32;
            __syncthreads();
            // ---- stage Xs: x values for this 32-k window (4 x rows) ----
            if (tid < 128) {
                int xr = tid >> 5, bc = (tid & 31) * 4;
                *(float4*)&Xs[xr][bc] =
                    *(const float4*)&xTi[(size_t)(kk * 4 + xr) * B_TOT + b0 + bc];
            }
            // ---- stage B: 128x32 G slice -> bf16 hi/lo in LDS ----
            {
                float4 f0 = *(const float4*)&Gr[k0 + 0];
                float4 f1 = *(const float4*)&Gr[k0 + 4];
                float4 f2 = *(const float4*)&Gr[k0 + 8];
                float4 f3 = *(const float4*)&Gr[k0 + 12];
                u32x4 H0, L0, H1, L1;
                uint2 p;
                p = split2(f0.x, f0.y); H0.x = p.x; L0.x = p.y;
                p = split2(f0.z, f0.w); H0.y = p.x; L0.y = p.y;
                p = split2(f1.x, f1.y); H0.z = p.x; L0.z = p.y;
                p = split2(f1.z, f1.w); H0.w = p.x; L0.w = p.y;
                p = split2(f2.x, f2.y); H1.x = p.x; L1.x = p.y;
                p = split2(f2.z, f2.w); H1.y = p.x; L1.y = p.y;
                p = split2(f3.x, f3.y); H1.z = p.x; L1.z = p.y;
                p = split2(f3.z, f3.w); H1.w = p.x; L1.w = p.y;
                *(u32x4*)&Bhi[so * 32 + sh] = H0;
                *(u32x4*)&Bhi[so * 32 + sh + 8] = H1;
                *(u32x4*)&Blo[so * 32 + sh] = L0;
                *(u32x4*)&Blo[so * 32 + sh + 8] = L1;
            }
            __syncthreads();

            // ---- B fragments from LDS ----
            bf16x8 bh[4], bl[4];
#pragma unroll
            for (int nf = 0; nf < 4; ++nf) {
                int n = wn + nf * 16 + l15;
                bh[nf] = *(const bf16x8*)&Bhi[n * 32 + quad * 8];
                bl[nf] = *(const bf16x8*)&Blo[n * 32 + quad * 8];
            }

            // ---- A fragments generated in registers + MFMA ----
#pragma unroll
            for (int mf = 0; mf < 4; ++mf) {
                float xv = Xs[quad][wm + mf * 16 + l15];
                u32x4 AH, AL;
                uint2 p;
                p = split2(e[mf][0] * xv, e[mf][1] * xv); AH.x = p.x; AL.x = p.y;
                p = split2(e[mf][2] * xv, e[mf][3] * xv); AH.y = p.x; AL.y = p.y;
                p = split2(e[mf][4] * xv, e[mf][5] * xv); AH.z = p.x; AL.z = p.y;
                p = split2(e[mf][6] * xv, e[mf][7] * xv); AH.w = p.x; AL.w = p.y;
                bf16x8 Ah = __builtin_bit_cast(bf16x8, AH);
                bf16x8 Al = __builtin_bit_cast(bf16x8, AL);
#pragma unroll
                for (int nf = 0; nf < 4; ++nf) {
                    acc[mf][nf] = __builtin_amdgcn_mfma_f32_16x16x32_bf16(Ah, bh[nf], acc[mf][nf], 0, 0, 0);
                    acc[mf][nf] = __builtin_amdgcn_mfma_f32_16x16x32_bf16(Ah, bl[nf], acc[mf][nf], 0, 0, 0);
                    acc[mf][nf] = __builtin_amdgcn_mfma_f32_16x16x32_bf16(Al, bh[nf], acc[mf][nf], 0, 0, 0);
                }
            }
        }
    }

    // ---- epilogue: C/D layout col=lane&15, row=quad*4+reg ----
#pragma unroll
    for (int nf = 0; nf < 4; ++nf) {
        int col = o0 + wn + nf * 16 + l15;
        float bv = bias[i * LOUT + col];
#pragma unroll
        for (int mf = 0; mf < 4; ++mf) {
#pragma unroll
            for (int reg = 0; reg < 4; ++reg) {
                int row = b0 + wm + mf * 16 + quad * 4 + reg;
                out[(size_t)row * D_OUT + i * LOUT + col] = acc[mf][nf][reg] + bv;
            }
        }
    }
}

extern "C" void kernel_launch(void* const* d_in, const int* in_sizes, int n_in,
                              void* d_out, int out_size, void* d_ws, size_t ws_size,
                              hipStream_t stream) {
    const float* x    = (const float*)d_in[0];
    const float* g0   = (const float*)d_in[1];
    const float* g1   = (const float*)d_in[2];
    const float* g2   = (const float*)d_in[3];
    const float* g3   = (const float*)d_in[4];
    const float* bias = (const float*)d_in[5];
    float* out = (float*)d_out;
    float* ws = (float*)d_ws;

    float* xT   = ws + WS_XT;
    float* ghat = ws + WS_GHAT;
    float* S    = ws + WS_S;
    float* envT = ws + WS_ENVT;

    k_transpose<<<dim3(128, 64), dim3(32, 8), 0, stream>>>(x, xT);
    k_reduce_g<<<dim3(16, 8, 4), 256, 0, stream>>>(g0, g1, g2, g3, ghat);
    k_s<<<dim3(1024, 4), 256, 0, stream>>>(x, ghat, S);
    k_env<<<1024, 256, 0, stream>>>(S, envT);
    k_gemm_mfma<<<512, 256, 0, stream>>>(g0, g1, g2, g3, xT, envT, bias, out);
}